// Round 8
// baseline (425.157 us; speedup 1.0000x reference)
//
#include <hip/hip_runtime.h>
#include <hip/hip_bf16.h>

typedef __bf16 bf16;
typedef bf16 bf16x2 __attribute__((ext_vector_type(2)));
typedef bf16 bf16x4 __attribute__((ext_vector_type(4)));
typedef bf16 bf16x8 __attribute__((ext_vector_type(8)));
typedef float floatx4 __attribute__((ext_vector_type(4)));

#define MFMA_BF16(a, b, c) __builtin_amdgcn_mfma_f32_16x16x32_bf16((a), (b), (c), 0, 0, 0)

// ---------------------------------------------------------------------------
// fp32 -> bf16 elementwise convert (8 els/thread)
// ---------------------------------------------------------------------------
__global__ __launch_bounds__(256) void cvt_kernel(const float* __restrict__ in,
                                                  bf16* __restrict__ out, int n8) {
    int idx = blockIdx.x * 256 + threadIdx.x;
    if (idx >= n8) return;
    const float* src = in + (size_t)idx * 8;
    float4 f0 = *(const float4*)src;
    float4 f1 = *(const float4*)(src + 4);
    bf16x8 v = {(bf16)f0.x, (bf16)f0.y, (bf16)f0.z, (bf16)f0.w,
                (bf16)f1.x, (bf16)f1.y, (bf16)f1.z, (bf16)f1.w};
    *(bf16x8*)(out + (size_t)idx * 8) = v;
}

// ---------------------------------------------------------------------------
// fp32 [R][C] -> bf16 [C][R] transpose (32x32 LDS tiles)
// ---------------------------------------------------------------------------
__global__ __launch_bounds__(256) void trans_kernel(const float* __restrict__ in,
                                                    bf16* __restrict__ out, int R, int C) {
    __shared__ float tile[32][33];
    const int t = threadIdx.x;
    const int r0 = blockIdx.y * 32, c0 = blockIdx.x * 32;
    int r = t >> 3, c4 = (t & 7) * 4;
    float4 v = *(const float4*)&in[(size_t)(r0 + r) * C + c0 + c4];
    tile[r][c4 + 0] = v.x; tile[r][c4 + 1] = v.y;
    tile[r][c4 + 2] = v.z; tile[r][c4 + 3] = v.w;
    __syncthreads();
    int rp = t >> 3, cp = (t & 7) * 4;
    bf16x4 w = {(bf16)tile[cp + 0][rp], (bf16)tile[cp + 1][rp],
                (bf16)tile[cp + 2][rp], (bf16)tile[cp + 3][rp]};
    *(bf16x4*)&out[(size_t)(c0 + rp) * R + r0 + cp] = w;
}

// ---------------------------------------------------------------------------
// bf16 [4096][1024] (rows=b*1024+j, cols=h*64+d) -> Vt[b][h][d][j]
// ---------------------------------------------------------------------------
__global__ __launch_bounds__(256) void vtrans_kernel(const bf16* __restrict__ in,
                                                     bf16* __restrict__ out) {
    __shared__ bf16 tile[32][36];
    const int t = threadIdx.x;
    const int r0 = blockIdx.y * 32, c0 = blockIdx.x * 32;  // r=m, c=h*64+d
    int r = t >> 3, c4 = (t & 7) * 4;
    bf16x4 v = *(const bf16x4*)&in[(size_t)(r0 + r) * 1024 + c0 + c4];
    tile[r][c4 + 0] = v[0]; tile[r][c4 + 1] = v[1];
    tile[r][c4 + 2] = v[2]; tile[r][c4 + 3] = v[3];
    __syncthreads();
    int rp = t >> 3, cp = (t & 7) * 4;
    int hd = c0 + rp;                 // (h*64+d)
    int b = r0 >> 10, j = (r0 & 1023) + cp;
    bf16x4 w = {tile[cp + 0][rp], tile[cp + 1][rp], tile[cp + 2][rp], tile[cp + 3][rp]};
    *(bf16x4*)&out[(size_t)(b * 1024 + hd) * 1024 + j] = w;
}

// ---------------------------------------------------------------------------
// Centered talking-heads weights, transposed for the attn A-frag:
// WtcT[g][k] = Wt[k][g] - mean_g'(Wt[k][g']) for k<16; WtcT[g][16..31] = 0.
// Layout [16][32] bf16 so a_wt = 16B load at [l15][quad*8] (quad>=2 -> zeros).
// ---------------------------------------------------------------------------
__global__ __launch_bounds__(256) void prep_wt_kernel(const float* __restrict__ Wt,
                                                      bf16* __restrict__ WtcT) {
    const int t = threadIdx.x;        // 256 threads: g = t>>4, k = t&15
    const int g = t >> 4, k = t & 15;
    float s = 0.f;
#pragma unroll
    for (int gg = 0; gg < 16; ++gg) s += Wt[k * 16 + gg];
    WtcT[g * 32 + k] = (bf16)(Wt[k * 16 + g] - s * 0.0625f);
    WtcT[g * 32 + 16 + k] = (bf16)0.f;
}

// ---------------------------------------------------------------------------
// m93-style 128x128 GEMM, BK=32, 256 threads (4 waves, 64x64/wave, 4x4 MFMA).
// A [M][1024] bf16 row-major; B [N][1024] bf16 (pre-transposed, n-major).
// MODE 0: C[m*N+n].  MODE 1 (KV): n<1024 -> C (K), n>=1024 -> V [m][n-1024].
// ---------------------------------------------------------------------------
template <int MODE>
__global__ __launch_bounds__(256) void gemm128(const bf16* __restrict__ A,
                                               const bf16* __restrict__ B,
                                               bf16* __restrict__ C,
                                               bf16* __restrict__ V, int N) {
    __shared__ bf16 As[128 * 40];
    __shared__ bf16 Bs[128 * 40];
    const int t = threadIdx.x;
    const int wv = t >> 6, lane = t & 63, quad = lane >> 4, l15 = lane & 15;
    const int wr = wv >> 1, wc = wv & 1;
    const int m0 = blockIdx.y * 128, n0 = blockIdx.x * 128;
    const int ra = t >> 1, kc = (t & 1) * 16;

    floatx4 acc[4][4] = {};

    for (int k0 = 0; k0 < 1024; k0 += 32) {
        bf16x8 a0 = *(const bf16x8*)&A[(size_t)(m0 + ra) * 1024 + k0 + kc];
        bf16x8 a1 = *(const bf16x8*)&A[(size_t)(m0 + ra) * 1024 + k0 + kc + 8];
        bf16x8 b0 = *(const bf16x8*)&B[(size_t)(n0 + ra) * 1024 + k0 + kc];
        bf16x8 b1 = *(const bf16x8*)&B[(size_t)(n0 + ra) * 1024 + k0 + kc + 8];
        __syncthreads();
        *(bf16x8*)&As[ra * 40 + kc] = a0;
        *(bf16x8*)&As[ra * 40 + kc + 8] = a1;
        *(bf16x8*)&Bs[ra * 40 + kc] = b0;
        *(bf16x8*)&Bs[ra * 40 + kc + 8] = b1;
        __syncthreads();
        bf16x8 af[4], bfr[4];
#pragma unroll
        for (int mt = 0; mt < 4; ++mt)
            af[mt] = *(bf16x8*)&As[(wr * 64 + mt * 16 + l15) * 40 + quad * 8];
#pragma unroll
        for (int nt = 0; nt < 4; ++nt)
            bfr[nt] = *(bf16x8*)&Bs[(wc * 64 + nt * 16 + l15) * 40 + quad * 8];
#pragma unroll
        for (int mt = 0; mt < 4; ++mt)
#pragma unroll
            for (int nt = 0; nt < 4; ++nt)
                acc[mt][nt] = MFMA_BF16(af[mt], bfr[nt], acc[mt][nt]);
    }
#pragma unroll
    for (int mt = 0; mt < 4; ++mt)
#pragma unroll
        for (int nt = 0; nt < 4; ++nt)
#pragma unroll
            for (int r = 0; r < 4; ++r) {
                int m = m0 + wr * 64 + mt * 16 + quad * 4 + r;
                int n = n0 + wc * 64 + nt * 16 + l15;
                bf16 val = (bf16)acc[mt][nt][r];
                if (MODE == 0) {
                    C[(size_t)m * N + n] = val;
                } else {
                    if (n < 1024) C[(size_t)m * 1024 + n] = val;
                    else          V[(size_t)m * 1024 + (n - 1024)] = val;
                }
            }
}

// ---------------------------------------------------------------------------
// Main fused attention with IN-KERNEL softmax denominators (denom_kernel
// deleted). Logical grid (i16=64, b=4, jsplit=2) = 512 blocks, 8 waves.
//
// PASS 1 (barrier-free): each wave sweeps the FULL j range for its own
// 2 heads x 16 i-rows, accumulating sum_j exp(S) in registers; 4-step
// butterfly over the 16-lane group leaves the sum in every lane ->
// invl = 1/sum. Redundant across the 2 jz-halves (zero-sync tradeoff).
// Replaces: denom kernel launch + L memset + 2M atomics + L roundtrip +
// duplicate Q loads. Also warms K into L2 for pass 2.
//
// PASS 2: R7's 3-stage single-barrier pipeline, unchanged:
//     S[jt] || MIX[jt-1] || PV[jt-2] ; one barrier.
// LDS: Buf1 2x20480 + Buf2 2x20480 = 81920 B (2 blocks/CU, full 160 KiB).
// Buf2 rot layout (R4-verified): idx(g,p) = g*640 + ((g>>2)&1)*8 + p;
// Zbuf = Buf2[0]'s rot-hole [2560..2568).
// ---------------------------------------------------------------------------
__global__ __launch_bounds__(512, 4) void attn_kernel(const bf16* __restrict__ Qb,
                                                      const bf16* __restrict__ Kb,
                                                      const bf16* __restrict__ Vt,
                                                      const bf16* __restrict__ WtcT,
                                                      const float* __restrict__ gamma,
                                                      const float* __restrict__ beta,
                                                      float* __restrict__ out) {
    __shared__ bf16 Buf1[2][512 * 20];     // [buf][point p=i*32+jl][16 h + 4 pad]
    __shared__ bf16 Buf2[2][16 * 640];     // [buf][g][rot(g) + i*40 + jl]
    const int t = threadIdx.x;
    const int wv = t >> 6, lane = t & 63, quad = lane >> 4, l15 = lane & 15;
    // XCD-aware swizzle (bijective: 512 = 8 * 64).
    unsigned n = blockIdx.x + (blockIdx.y << 6) + (blockIdx.z << 8);   // 512 total
    unsigned o_idx = (n & 7) * 64 + (n >> 3);
    const int i0 = (o_idx & 63) * 16;
    const int b  = (o_idx >> 6) & 3;
    const int jz = o_idx >> 8;
    const float scale = 0.125f;

    if (t < 8) Buf2[0][2560 + t] = (bf16)0.f;   // zero region in buf0's rot-hole
    const bf16* Zbuf = &Buf2[0][2560];

    // A-frag of centered Wt^T: one 16B load (quad>=2 slots are stored zeros).
    bf16x8 a_wt = *(const bf16x8*)&WtcT[l15 * 32 + quad * 8];
    float gq[4], bq[4];
#pragma unroll
    for (int r = 0; r < 4; ++r) { gq[r] = gamma[quad * 4 + r]; bq[r] = beta[quad * 4 + r]; }

    bf16x8 qa[2][2];
#pragma unroll
    for (int hh = 0; hh < 2; ++hh) {
        int h = wv * 2 + hh;
        const bf16* qp = Qb + (size_t)(b * 1024 + i0 + l15) * 1024 + h * 64 + quad * 8;
        qa[hh][0] = *(const bf16x8*)qp;
        qa[hh][1] = *(const bf16x8*)(qp + 32);
    }

    const bf16* Kbase = Kb + (size_t)b * 1024 * 1024;
    const bf16* Vbase = Vt + (size_t)b * 16 * 64 * 1024;

    // ---- PASS 1: softmax denominators in-register (replaces denom_kernel) ----
    float invl[2][4];
    {
        floatx4 se[2] = {};
#pragma unroll 2
        for (int jt = 0; jt < 64; ++jt) {
            int j = jt * 16 + l15;
            const bf16* kr = Kbase + (size_t)j * 1024 + quad * 8;
#pragma unroll
            for (int hh = 0; hh < 2; ++hh) {
                const bf16* kp = kr + (wv * 2 + hh) * 64;
                floatx4 c = {0.f, 0.f, 0.f, 0.f};
                c = MFMA_BF16(qa[hh][0], *(const bf16x8*)kp, c);
                c = MFMA_BF16(qa[hh][1], *(const bf16x8*)(kp + 32), c);
#pragma unroll
                for (int r = 0; r < 4; ++r) se[hh][r] += __expf(c[r] * scale);
            }
        }
#pragma unroll
        for (int hh = 0; hh < 2; ++hh)
#pragma unroll
            for (int r = 0; r < 4; ++r) {
                float s = se[hh][r];
                s += __shfl_xor(s, 1); s += __shfl_xor(s, 2);
                s += __shfl_xor(s, 4); s += __shfl_xor(s, 8);
                invl[hh][r] = 1.f / s;       // every lane holds the row sum
            }
    }

    floatx4 o[2][4] = {};

    // --- stage bodies ---
    auto S_phase = [&](int jt) {   // QK^T -> w=exp*invl -> Buf1[jt&1]
        bf16* B1 = Buf1[jt & 1];
        const int j0 = jz * 512 + jt * 32;
#pragma unroll
        for (int ns = 0; ns < 2; ++ns) {
            floatx4 cw[2];
#pragma unroll
            for (int hh = 0; hh < 2; ++hh) {
                int h = wv * 2 + hh;
                const bf16* kp = Kbase + (size_t)(j0 + ns * 16 + l15) * 1024 + h * 64 + quad * 8;
                floatx4 c = {0.f, 0.f, 0.f, 0.f};
                c = MFMA_BF16(qa[hh][0], *(const bf16x8*)kp, c);
                c = MFMA_BF16(qa[hh][1], *(const bf16x8*)(kp + 32), c);
                cw[hh] = c;
            }
#pragma unroll
            for (int r = 0; r < 4; ++r) {
                bf16x2 pk = {(bf16)(__expf(cw[0][r] * scale) * invl[0][r]),
                             (bf16)(__expf(cw[1][r] * scale) * invl[1][r])};
                *(bf16x2*)&B1[((quad * 4 + r) * 32 + ns * 16 + l15) * 20 + wv * 2] = pk;
            }
        }
    };
    auto MIX = [&](int jt) {       // talking-heads mix + LN: Buf1[jt&1] -> Buf2[jt&1]
        const bf16* B1 = Buf1[jt & 1];
        bf16* B2 = Buf2[jt & 1];
#pragma unroll
        for (int grp = 0; grp < 4; ++grp) {
            int gi = wv * 4 + grp, ig = gi >> 1, jb = (gi & 1) * 16;
            int p = ig * 32 + jb + l15;
            const bf16* src = (quad < 2) ? &B1[p * 20 + quad * 8] : Zbuf;
            floatx4 c = {0.f, 0.f, 0.f, 0.f};
            c = MFMA_BF16(a_wt, *(const bf16x8*)src, c);
            float s2 = c[0] * c[0] + c[1] * c[1] + c[2] * c[2] + c[3] * c[3];
            s2 += __shfl_xor(s2, 16);
            s2 += __shfl_xor(s2, 32);
            float rs = rsqrtf(s2 * 0.0625f + 1e-5f);
#pragma unroll
            for (int r = 0; r < 4; ++r) {
                float w2 = c[r] * rs * gq[r] + bq[r];
                B2[(quad * 4 + r) * 640 + (quad & 1) * 8 + ig * 40 + jb + l15] = (bf16)w2;
            }
        }
    };
    auto PV = [&](int jt) {        // O += w2[jt] * V[jt], from Buf2[jt&1]
        const bf16* B2 = Buf2[jt & 1];
        const int j0 = jz * 512 + jt * 32;
#pragma unroll
        for (int hh = 0; hh < 2; ++hh) {
            int g = wv * 2 + hh;
            bf16x8 a = *(const bf16x8*)&B2[g * 640 + ((g >> 2) & 1) * 8 + l15 * 40 + quad * 8];
#pragma unroll
            for (int dt = 0; dt < 4; ++dt) {
                const bf16* vp = Vbase + (size_t)(g * 64 + dt * 16 + l15) * 1024 + j0 + quad * 8;
                o[hh][dt] = MFMA_BF16(a, *(const bf16x8*)vp, o[hh][dt]);
            }
        }
    };

    // --- PASS 2: 3-stage pipeline, one barrier per phase ---
    S_phase(0);
    __syncthreads();
    S_phase(1); MIX(0);
    __syncthreads();
    for (int jt = 2; jt < 16; ++jt) {
        S_phase(jt); PV(jt - 2); MIX(jt - 1);
        __syncthreads();
    }
    PV(14); MIX(15);
    __syncthreads();
    PV(15);

#pragma unroll
    for (int hh = 0; hh < 2; ++hh) {
        int g = wv * 2 + hh;
#pragma unroll
        for (int dt = 0; dt < 4; ++dt)
#pragma unroll
            for (int r = 0; r < 4; ++r)
                atomicAdd(&out[(size_t)(b * 1024 + i0 + quad * 4 + r) * 1024 +
                               g * 64 + dt * 16 + l15], o[hh][dt][r]);
    }
}

extern "C" void kernel_launch(void* const* d_in, const int* in_sizes, int n_in,
                              void* d_out, int out_size, void* d_ws, size_t ws_size,
                              hipStream_t stream) {
    const float* x     = (const float*)d_in[0];
    const float* ctx   = (const float*)d_in[1];
    const float* Wq    = (const float*)d_in[2];
    const float* Wkv   = (const float*)d_in[3];
    const float* Wt    = (const float*)d_in[4];
    const float* gamma = (const float*)d_in[5];
    const float* beta  = (const float*)d_in[6];
    float* out = (float*)d_out;

    // ws layout (bf16 els): xb 4M | ctxb 4M | WqT 1M | WkvT 2M | Qb 4M | Kb 4M |
    //                       Vr 4M | Vt 4M   => ~54 MB  (L buffer removed)
    // WtcT (512 bf16) reuses the head of Vr: Vr is dead after vtrans_kernel.
    bf16* xb   = (bf16*)d_ws;
    bf16* cb   = xb + (size_t)4 * 1024 * 1024;
    bf16* WqT  = cb + (size_t)4 * 1024 * 1024;
    bf16* WkvT = WqT + (size_t)1024 * 1024;
    bf16* Qb   = WkvT + (size_t)2048 * 1024;
    bf16* Kb   = Qb + (size_t)4 * 1024 * 1024;
    bf16* Vr   = Kb + (size_t)4 * 1024 * 1024;
    bf16* Vt   = Vr + (size_t)4 * 1024 * 1024;
    bf16* WtcT = Vr;

    hipMemsetAsync(out, 0, (size_t)out_size * sizeof(float), stream);

    cvt_kernel<<<2048, 256, 0, stream>>>(x, xb, 524288);
    cvt_kernel<<<2048, 256, 0, stream>>>(ctx, cb, 524288);
    trans_kernel<<<dim3(32, 32), 256, 0, stream>>>(Wq, WqT, 1024, 1024);
    trans_kernel<<<dim3(64, 32), 256, 0, stream>>>(Wkv, WkvT, 1024, 2048);

    gemm128<0><<<dim3(8, 32), 256, 0, stream>>>(xb, WqT, Qb, nullptr, 1024);
    gemm128<1><<<dim3(16, 32), 256, 0, stream>>>(cb, WkvT, Kb, Vr, 2048);
    vtrans_kernel<<<dim3(32, 128), 256, 0, stream>>>(Vr, Vt);
    prep_wt_kernel<<<1, 256, 0, stream>>>(Wt, WtcT);

    attn_kernel<<<dim3(64, 4, 2), 512, 0, stream>>>(Qb, Kb, Vt, WtcT, gamma, beta, out);
}

// Round 9
// 341.959 us; speedup vs baseline: 1.2433x; 1.2433x over previous
//
#include <hip/hip_runtime.h>
#include <hip/hip_bf16.h>

typedef __bf16 bf16;
typedef bf16 bf16x2 __attribute__((ext_vector_type(2)));
typedef bf16 bf16x4 __attribute__((ext_vector_type(4)));
typedef bf16 bf16x8 __attribute__((ext_vector_type(8)));
typedef float floatx4 __attribute__((ext_vector_type(4)));

#define MFMA_BF16(a, b, c) __builtin_amdgcn_mfma_f32_16x16x32_bf16((a), (b), (c), 0, 0, 0)

// ---------------------------------------------------------------------------
// fp32 -> bf16 elementwise convert, BOTH tensors in one launch (task decode).
// x: 524288 groups of 8; ctx: 524288 groups. 4096 blocks x 256 thr.
// ---------------------------------------------------------------------------
__global__ __launch_bounds__(256) void cvt_both_kernel(const float* __restrict__ x,
                                                       const float* __restrict__ ctx,
                                                       bf16* __restrict__ xb,
                                                       bf16* __restrict__ cb) {
    int idx = blockIdx.x * 256 + threadIdx.x;
    const float* in; bf16* out;
    if (idx < 524288) { in = x; out = xb; }
    else              { in = ctx; out = cb; idx -= 524288; }
    const float* src = in + (size_t)idx * 8;
    float4 f0 = *(const float4*)src;
    float4 f1 = *(const float4*)(src + 4);
    bf16x8 v = {(bf16)f0.x, (bf16)f0.y, (bf16)f0.z, (bf16)f0.w,
                (bf16)f1.x, (bf16)f1.y, (bf16)f1.z, (bf16)f1.w};
    *(bf16x8*)(out + (size_t)idx * 8) = v;
}

// ---------------------------------------------------------------------------
// fp32 [R][C] -> bf16 [C][R] transpose, Wq AND Wkv in one launch.
// Blocks 0..1023: Wq (32x32 tiles); 1024..3071: Wkv (64x32 tiles).
// ---------------------------------------------------------------------------
__global__ __launch_bounds__(256) void trans_both_kernel(const float* __restrict__ Wq,
                                                         const float* __restrict__ Wkv,
                                                         bf16* __restrict__ WqT,
                                                         bf16* __restrict__ WkvT) {
    __shared__ float tile[32][33];
    const int t = threadIdx.x;
    int blk = blockIdx.x;
    const float* in; bf16* out; int R, C, bx, by;
    if (blk < 1024) { in = Wq;  out = WqT;  R = 1024; C = 1024; bx = blk & 31; by = blk >> 5; }
    else { blk -= 1024; in = Wkv; out = WkvT; R = 1024; C = 2048; bx = blk & 63; by = blk >> 6; }
    const int r0 = by * 32, c0 = bx * 32;
    int r = t >> 3, c4 = (t & 7) * 4;
    float4 v = *(const float4*)&in[(size_t)(r0 + r) * C + c0 + c4];
    tile[r][c4 + 0] = v.x; tile[r][c4 + 1] = v.y;
    tile[r][c4 + 2] = v.z; tile[r][c4 + 3] = v.w;
    __syncthreads();
    int rp = t >> 3, cp = (t & 7) * 4;
    bf16x4 w = {(bf16)tile[cp + 0][rp], (bf16)tile[cp + 1][rp],
                (bf16)tile[cp + 2][rp], (bf16)tile[cp + 3][rp]};
    *(bf16x4*)&out[(size_t)(c0 + rp) * R + r0 + cp] = w;
}

// ---------------------------------------------------------------------------
// vtrans (blocks 0..4095) + prep_wt (block 4096) in one launch.
// vtrans: bf16 [4096][1024] (rows=b*1024+j, cols=h*64+d) -> Vt[b][h][d][j].
// prep_wt: WtcT[g][k] = Wt[k][g] - mean_g'(Wt[k][g']) for k<16; zeros k>=16.
// WtcT no longer aliases Vr (race-free with concurrent vtrans blocks).
// ---------------------------------------------------------------------------
__global__ __launch_bounds__(256) void vtrans_prep_kernel(const bf16* __restrict__ in,
                                                          bf16* __restrict__ out,
                                                          const float* __restrict__ Wt,
                                                          bf16* __restrict__ WtcT) {
    const int t = threadIdx.x;
    if (blockIdx.x == 4096) {            // prep_wt task
        const int g = t >> 4, k = t & 15;
        float s = 0.f;
#pragma unroll
        for (int gg = 0; gg < 16; ++gg) s += Wt[k * 16 + gg];
        WtcT[g * 32 + k] = (bf16)(Wt[k * 16 + g] - s * 0.0625f);
        WtcT[g * 32 + 16 + k] = (bf16)0.f;
        return;
    }
    __shared__ bf16 tile[32][36];
    const int bx = blockIdx.x & 31, by = blockIdx.x >> 5;
    const int r0 = by * 32, c0 = bx * 32;  // r=m, c=h*64+d
    int r = t >> 3, c4 = (t & 7) * 4;
    bf16x4 v = *(const bf16x4*)&in[(size_t)(r0 + r) * 1024 + c0 + c4];
    tile[r][c4 + 0] = v[0]; tile[r][c4 + 1] = v[1];
    tile[r][c4 + 2] = v[2]; tile[r][c4 + 3] = v[3];
    __syncthreads();
    int rp = t >> 3, cp = (t & 7) * 4;
    int hd = c0 + rp;                 // (h*64+d)
    int b = r0 >> 10, j = (r0 & 1023) + cp;
    bf16x4 w = {tile[cp + 0][rp], tile[cp + 1][rp], tile[cp + 2][rp], tile[cp + 3][rp]};
    *(bf16x4*)&out[(size_t)(b * 1024 + hd) * 1024 + j] = w;
}

// ---------------------------------------------------------------------------
// MERGED GEMM launch: Q-projection AND KV-projection in ONE 768-block grid
// so every CU holds 3 GEMM blocks (was: 256-block launch = 1/CU, serialized
// with a 512-block launch). m93-style 128x128, BK=32, 256 thr, 4x4 MFMA/wave.
// Blocks 0..255:   Qb = xb @ WqT   (N=1024; bx=blk&7,  by=blk>>3)
// Blocks 256..767: [K|V] = cb @ WkvT (N=2048; bx=blk&15, by=blk>>4),
//                  n<1024 -> Kb, n>=1024 -> Vr.
// ---------------------------------------------------------------------------
__global__ __launch_bounds__(256) void gemm_all(const bf16* __restrict__ xb,
                                                const bf16* __restrict__ cb,
                                                const bf16* __restrict__ WqT,
                                                const bf16* __restrict__ WkvT,
                                                bf16* __restrict__ Qb,
                                                bf16* __restrict__ Kb,
                                                bf16* __restrict__ Vr) {
    __shared__ bf16 As[128 * 40];
    __shared__ bf16 Bs[128 * 40];
    const int t = threadIdx.x;
    const int wv = t >> 6, lane = t & 63, quad = lane >> 4, l15 = lane & 15;
    const int wr = wv >> 1, wc = wv & 1;
    int blk = blockIdx.x;
    const bf16 *A, *B; bool kv; int bx, by;
    if (blk < 256) { A = xb; B = WqT; kv = false; bx = blk & 7; by = blk >> 3; }
    else { blk -= 256; A = cb; B = WkvT; kv = true; bx = blk & 15; by = blk >> 4; }
    const int m0 = by * 128, n0 = bx * 128;
    const int ra = t >> 1, kc = (t & 1) * 16;

    floatx4 acc[4][4] = {};

    for (int k0 = 0; k0 < 1024; k0 += 32) {
        bf16x8 a0 = *(const bf16x8*)&A[(size_t)(m0 + ra) * 1024 + k0 + kc];
        bf16x8 a1 = *(const bf16x8*)&A[(size_t)(m0 + ra) * 1024 + k0 + kc + 8];
        bf16x8 b0 = *(const bf16x8*)&B[(size_t)(n0 + ra) * 1024 + k0 + kc];
        bf16x8 b1 = *(const bf16x8*)&B[(size_t)(n0 + ra) * 1024 + k0 + kc + 8];
        __syncthreads();
        *(bf16x8*)&As[ra * 40 + kc] = a0;
        *(bf16x8*)&As[ra * 40 + kc + 8] = a1;
        *(bf16x8*)&Bs[ra * 40 + kc] = b0;
        *(bf16x8*)&Bs[ra * 40 + kc + 8] = b1;
        __syncthreads();
        bf16x8 af[4], bfr[4];
#pragma unroll
        for (int mt = 0; mt < 4; ++mt)
            af[mt] = *(bf16x8*)&As[(wr * 64 + mt * 16 + l15) * 40 + quad * 8];
#pragma unroll
        for (int nt = 0; nt < 4; ++nt)
            bfr[nt] = *(bf16x8*)&Bs[(wc * 64 + nt * 16 + l15) * 40 + quad * 8];
#pragma unroll
        for (int mt = 0; mt < 4; ++mt)
#pragma unroll
            for (int nt = 0; nt < 4; ++nt)
                acc[mt][nt] = MFMA_BF16(af[mt], bfr[nt], acc[mt][nt]);
    }
#pragma unroll
    for (int mt = 0; mt < 4; ++mt)
#pragma unroll
        for (int nt = 0; nt < 4; ++nt)
#pragma unroll
            for (int r = 0; r < 4; ++r) {
                int m = m0 + wr * 64 + mt * 16 + quad * 4 + r;
                int n = n0 + wc * 64 + nt * 16 + l15;
                bf16 val = (bf16)acc[mt][nt][r];
                if (!kv) {
                    Qb[(size_t)m * 1024 + n] = val;
                } else {
                    if (n < 1024) Kb[(size_t)m * 1024 + n] = val;
                    else          Vr[(size_t)m * 1024 + (n - 1024)] = val;
                }
            }
}

// ---------------------------------------------------------------------------
// Softmax denominators: L[b][h][i] = sum_j exp(q.k*scale).
// grid (i32=32, b=4, jsplit=16) = 2048 blocks, 256 thr = 4 waves.
// XCD swizzle (R3-verified). hh-outer keeps live state small.
// ---------------------------------------------------------------------------
__global__ __launch_bounds__(256, 4) void denom_kernel(const bf16* __restrict__ Qb,
                                                       const bf16* __restrict__ Kb,
                                                       float* __restrict__ L) {
    const int t = threadIdx.x;
    const int wv = t >> 6, lane = t & 63, quad = lane >> 4, l15 = lane & 15;
    unsigned n = blockIdx.x + (blockIdx.y << 5) + (blockIdx.z << 7);   // 2048 total
    unsigned o = (n & 7) * 256 + (n >> 3);
    const int i0 = (o & 31) * 32;
    const int b  = (o >> 5) & 3;
    const int jz = o >> 7;
    const float scale = 0.125f;
    const bf16* Kbase = Kb + (size_t)b * 1024 * 1024;

    for (int hh = 0; hh < 4; ++hh) {
        const int h = wv * 4 + hh;
        bf16x8 qa[2][2];
#pragma unroll
        for (int it = 0; it < 2; ++it) {
            const bf16* qp = Qb + (size_t)(b * 1024 + i0 + it * 16 + l15) * 1024 +
                             h * 64 + quad * 8;
            qa[it][0] = *(const bf16x8*)qp;
            qa[it][1] = *(const bf16x8*)(qp + 32);
        }
        floatx4 se[2] = {};
#pragma unroll
        for (int jt = 0; jt < 4; ++jt) {
            int j = jz * 64 + jt * 16 + l15;
            const bf16* kp = Kbase + (size_t)j * 1024 + h * 64 + quad * 8;
            bf16x8 k0 = *(const bf16x8*)kp;
            bf16x8 k1 = *(const bf16x8*)(kp + 32);
#pragma unroll
            for (int it = 0; it < 2; ++it) {
                floatx4 c = {0.f, 0.f, 0.f, 0.f};
                c = MFMA_BF16(qa[it][0], k0, c);
                c = MFMA_BF16(qa[it][1], k1, c);
#pragma unroll
                for (int r = 0; r < 4; ++r) se[it][r] += __expf(c[r] * scale);
            }
        }
#pragma unroll
        for (int it = 0; it < 2; ++it)
#pragma unroll
            for (int r = 0; r < 4; ++r) {
                float s = se[it][r];
                s += __shfl_xor(s, 1); s += __shfl_xor(s, 2);
                s += __shfl_xor(s, 4); s += __shfl_xor(s, 8);
                if (l15 == 0)
                    atomicAdd(&L[(size_t)(b * 16 + h) * 1024 + i0 + it * 16 +
                                 quad * 4 + r], s);
            }
    }
}

// ---------------------------------------------------------------------------
// Main fused attention — byte-identical to the R3-measured best (153.4 us):
// grid (64,4,2), 512 thr, 2 barriers/jt, LDS 40960 (rot-640 Buf2, zero-hole),
// XCD swizzle. VGPR 60 / SGPR 48, no spills.
// ---------------------------------------------------------------------------
__global__ __launch_bounds__(512, 4) void attn_kernel(const bf16* __restrict__ Qb,
                                                      const bf16* __restrict__ Kb,
                                                      const bf16* __restrict__ Vt,
                                                      const float* __restrict__ L,
                                                      const bf16* __restrict__ WtcT,
                                                      const float* __restrict__ gamma,
                                                      const float* __restrict__ beta,
                                                      float* __restrict__ out) {
    __shared__ bf16 Buf1[512 * 20];        // [point p=i*32+jl][16 h + 4 pad]
    __shared__ bf16 Buf2[16 * 640];        // [g][rot(g) + i*40 + jl]
    const int t = threadIdx.x;
    const int wv = t >> 6, lane = t & 63, quad = lane >> 4, l15 = lane & 15;
    unsigned n = blockIdx.x + (blockIdx.y << 6) + (blockIdx.z << 8);   // 512 total
    unsigned o_idx = (n & 7) * 64 + (n >> 3);
    const int i0 = (o_idx & 63) * 16;
    const int b  = (o_idx >> 6) & 3;
    const int jz = o_idx >> 8;
    const float scale = 0.125f;

    if (t < 8) Buf2[2560 + t] = (bf16)0.f;   // zero region in the rot-hole
    const bf16* Zbuf = &Buf2[2560];

    bf16x8 a_wt = *(const bf16x8*)&WtcT[l15 * 32 + quad * 8];
    float gq[4], bq[4];
#pragma unroll
    for (int r = 0; r < 4; ++r) { gq[r] = gamma[quad * 4 + r]; bq[r] = beta[quad * 4 + r]; }

    bf16x8 qa[2][2];
    float invl[2][4];
#pragma unroll
    for (int hh = 0; hh < 2; ++hh) {
        int h = wv * 2 + hh;
        const bf16* qp = Qb + (size_t)(b * 1024 + i0 + l15) * 1024 + h * 64 + quad * 8;
        qa[hh][0] = *(const bf16x8*)qp;
        qa[hh][1] = *(const bf16x8*)(qp + 32);
#pragma unroll
        for (int r = 0; r < 4; ++r)
            invl[hh][r] = 1.f / L[(size_t)(b * 16 + h) * 1024 + i0 + quad * 4 + r];
    }

    const bf16* Kbase = Kb + (size_t)b * 1024 * 1024;
    const bf16* Vbase = Vt + (size_t)b * 16 * 64 * 1024;
    floatx4 o[2][4] = {};

    for (int jt = 0; jt < 16; ++jt) {
        const int j0 = jz * 512 + jt * 32;
#pragma unroll
        for (int ns = 0; ns < 2; ++ns) {
            floatx4 cw[2];
#pragma unroll
            for (int hh = 0; hh < 2; ++hh) {
                int h = wv * 2 + hh;
                const bf16* kp = Kbase + (size_t)(j0 + ns * 16 + l15) * 1024 + h * 64 + quad * 8;
                floatx4 c = {0.f, 0.f, 0.f, 0.f};
                c = MFMA_BF16(qa[hh][0], *(const bf16x8*)kp, c);
                c = MFMA_BF16(qa[hh][1], *(const bf16x8*)(kp + 32), c);
                cw[hh] = c;
            }
#pragma unroll
            for (int r = 0; r < 4; ++r) {
                bf16x2 pk = {(bf16)(__expf(cw[0][r] * scale) * invl[0][r]),
                             (bf16)(__expf(cw[1][r] * scale) * invl[1][r])};
                *(bf16x2*)&Buf1[((quad * 4 + r) * 32 + ns * 16 + l15) * 20 + wv * 2] = pk;
            }
        }
        __syncthreads();
#pragma unroll
        for (int grp = 0; grp < 4; ++grp) {
            int gi = wv * 4 + grp, ig = gi >> 1, jb = (gi & 1) * 16;
            int p = ig * 32 + jb + l15;
            const bf16* src = (quad < 2) ? &Buf1[p * 20 + quad * 8] : Zbuf;
            floatx4 c = {0.f, 0.f, 0.f, 0.f};
            c = MFMA_BF16(a_wt, *(const bf16x8*)src, c);
            float s2 = c[0] * c[0] + c[1] * c[1] + c[2] * c[2] + c[3] * c[3];
            s2 += __shfl_xor(s2, 16);
            s2 += __shfl_xor(s2, 32);
            float rs = rsqrtf(s2 * 0.0625f + 1e-5f);
#pragma unroll
            for (int r = 0; r < 4; ++r) {
                float w2 = c[r] * rs * gq[r] + bq[r];
                Buf2[(quad * 4 + r) * 640 + (quad & 1) * 8 + ig * 40 + jb + l15] = (bf16)w2;
            }
        }
        __syncthreads();
#pragma unroll
        for (int hh = 0; hh < 2; ++hh) {
            int g = wv * 2 + hh;
            bf16x8 a = *(bf16x8*)&Buf2[g * 640 + ((g >> 2) & 1) * 8 + l15 * 40 + quad * 8];
#pragma unroll
            for (int dt = 0; dt < 4; ++dt) {
                const bf16* vp = Vbase + (size_t)(g * 64 + dt * 16 + l15) * 1024 + j0 + quad * 8;
                o[hh][dt] = MFMA_BF16(a, *(const bf16x8*)vp, o[hh][dt]);
            }
        }
    }
#pragma unroll
    for (int hh = 0; hh < 2; ++hh) {
        int g = wv * 2 + hh;
#pragma unroll
        for (int dt = 0; dt < 4; ++dt)
#pragma unroll
            for (int r = 0; r < 4; ++r)
                atomicAdd(&out[(size_t)(b * 1024 + i0 + quad * 4 + r) * 1024 +
                               g * 64 + dt * 16 + l15], o[hh][dt][r]);
    }
}

extern "C" void kernel_launch(void* const* d_in, const int* in_sizes, int n_in,
                              void* d_out, int out_size, void* d_ws, size_t ws_size,
                              hipStream_t stream) {
    const float* x     = (const float*)d_in[0];
    const float* ctx   = (const float*)d_in[1];
    const float* Wq    = (const float*)d_in[2];
    const float* Wkv   = (const float*)d_in[3];
    const float* Wt    = (const float*)d_in[4];
    const float* gamma = (const float*)d_in[5];
    const float* beta  = (const float*)d_in[6];
    float* out = (float*)d_out;

    // ws layout (bf16 els): xb 4M | ctxb 4M | WqT 1M | WkvT 2M | Qb 4M | Kb 4M |
    //                       Vr 4M | Vt 4M | L (64K fp32) | WtcT (512 bf16)
    bf16* xb   = (bf16*)d_ws;
    bf16* cb   = xb + (size_t)4 * 1024 * 1024;
    bf16* WqT  = cb + (size_t)4 * 1024 * 1024;
    bf16* WkvT = WqT + (size_t)1024 * 1024;
    bf16* Qb   = WkvT + (size_t)2048 * 1024;
    bf16* Kb   = Qb + (size_t)4 * 1024 * 1024;
    bf16* Vr   = Kb + (size_t)4 * 1024 * 1024;
    bf16* Vt   = Vr + (size_t)4 * 1024 * 1024;
    float* L   = (float*)(Vt + (size_t)4 * 1024 * 1024);
    bf16* WtcT = (bf16*)(L + (size_t)4 * 16 * 1024);   // no longer aliases Vr

    hipMemsetAsync(L, 0, (size_t)4 * 16 * 1024 * sizeof(float), stream);
    hipMemsetAsync(out, 0, (size_t)out_size * sizeof(float), stream);

    cvt_both_kernel<<<4096, 256, 0, stream>>>(x, ctx, xb, cb);
    trans_both_kernel<<<3072, 256, 0, stream>>>(Wq, Wkv, WqT, WkvT);

    gemm_all<<<768, 256, 0, stream>>>(xb, cb, WqT, WkvT, Qb, Kb, Vr);
    vtrans_prep_kernel<<<4097, 256, 0, stream>>>(Vr, Vt, Wt, WtcT);

    denom_kernel<<<dim3(32, 4, 16), 256, 0, stream>>>(Qb, Kb, L);
    attn_kernel<<<dim3(64, 4, 2), 512, 0, stream>>>(Qb, Kb, Vt, L, WtcT, gamma, beta, out);
}

// Round 10
// 328.448 us; speedup vs baseline: 1.2944x; 1.0411x over previous
//
#include <hip/hip_runtime.h>
#include <hip/hip_bf16.h>

typedef __bf16 bf16;
typedef bf16 bf16x2 __attribute__((ext_vector_type(2)));
typedef bf16 bf16x4 __attribute__((ext_vector_type(4)));
typedef bf16 bf16x8 __attribute__((ext_vector_type(8)));
typedef float floatx4 __attribute__((ext_vector_type(4)));

#define MFMA_BF16(a, b, c) __builtin_amdgcn_mfma_f32_16x16x32_bf16((a), (b), (c), 0, 0, 0)

// Async global->LDS DMA, 16 B per lane. LDS dest = uniform base + lane*16B
// (hardware rule, learn_hip m104); global src is per-lane.
__device__ __forceinline__ void gload16(const bf16* gsrc, bf16* ldst) {
    __builtin_amdgcn_global_load_lds(
        (__attribute__((address_space(1))) void*)const_cast<bf16*>(gsrc),
        (__attribute__((address_space(3))) void*)ldst,
        16, 0, 0);
}

// ---------------------------------------------------------------------------
// MERGED prep: cvt (blocks 0..4095: x then ctx, 8 els/thread) +
// weight transpose (blocks 4096..7167: Wq 1024 tiles, Wkv 2048 tiles).
// ---------------------------------------------------------------------------
__global__ __launch_bounds__(256) void prep_kernel(const float* __restrict__ x,
                                                   const float* __restrict__ ctx,
                                                   const float* __restrict__ Wq,
                                                   const float* __restrict__ Wkv,
                                                   bf16* __restrict__ xb,
                                                   bf16* __restrict__ cb,
                                                   bf16* __restrict__ WqT,
                                                   bf16* __restrict__ WkvT) {
    __shared__ float tile[32][33];
    const int t = threadIdx.x;
    int blk = blockIdx.x;
    if (blk < 4096) {                       // ---- cvt task ----
        int idx = blk * 256 + t;
        const float* in; bf16* out;
        if (idx < 524288) { in = x; out = xb; }
        else              { in = ctx; out = cb; idx -= 524288; }
        const float* src = in + (size_t)idx * 8;
        float4 f0 = *(const float4*)src;
        float4 f1 = *(const float4*)(src + 4);
        bf16x8 v = {(bf16)f0.x, (bf16)f0.y, (bf16)f0.z, (bf16)f0.w,
                    (bf16)f1.x, (bf16)f1.y, (bf16)f1.z, (bf16)f1.w};
        *(bf16x8*)(out + (size_t)idx * 8) = v;
        return;
    }
    blk -= 4096;                            // ---- transpose task ----
    const float* in; bf16* out; int R, C, bx, by;
    if (blk < 1024) { in = Wq;  out = WqT;  R = 1024; C = 1024; bx = blk & 31; by = blk >> 5; }
    else { blk -= 1024; in = Wkv; out = WkvT; R = 1024; C = 2048; bx = blk & 63; by = blk >> 6; }
    const int r0 = by * 32, c0 = bx * 32;
    int r = t >> 3, c4 = (t & 7) * 4;
    float4 v = *(const float4*)&in[(size_t)(r0 + r) * C + c0 + c4];
    tile[r][c4 + 0] = v.x; tile[r][c4 + 1] = v.y;
    tile[r][c4 + 2] = v.z; tile[r][c4 + 3] = v.w;
    __syncthreads();
    int rp = t >> 3, cp = (t & 7) * 4;
    bf16x4 w = {(bf16)tile[cp + 0][rp], (bf16)tile[cp + 1][rp],
                (bf16)tile[cp + 2][rp], (bf16)tile[cp + 3][rp]};
    *(bf16x4*)&out[(size_t)(c0 + rp) * R + r0 + cp] = w;
}

// ---------------------------------------------------------------------------
// vtrans (blocks 0..4095) + prep_wt (block 4096) in one launch (R9-identical).
// ---------------------------------------------------------------------------
__global__ __launch_bounds__(256) void vtrans_prep_kernel(const bf16* __restrict__ in,
                                                          bf16* __restrict__ out,
                                                          const float* __restrict__ Wt,
                                                          bf16* __restrict__ WtcT) {
    const int t = threadIdx.x;
    if (blockIdx.x == 4096) {            // prep_wt task
        const int g = t >> 4, k = t & 15;
        float s = 0.f;
#pragma unroll
        for (int gg = 0; gg < 16; ++gg) s += Wt[k * 16 + gg];
        WtcT[g * 32 + k] = (bf16)(Wt[k * 16 + g] - s * 0.0625f);
        WtcT[g * 32 + 16 + k] = (bf16)0.f;
        return;
    }
    __shared__ bf16 tile[32][36];
    const int bx = blockIdx.x & 31, by = blockIdx.x >> 5;
    const int r0 = by * 32, c0 = bx * 32;  // r=m, c=h*64+d
    int r = t >> 3, c4 = (t & 7) * 4;
    bf16x4 v = *(const bf16x4*)&in[(size_t)(r0 + r) * 1024 + c0 + c4];
    tile[r][c4 + 0] = v[0]; tile[r][c4 + 1] = v[1];
    tile[r][c4 + 2] = v[2]; tile[r][c4 + 3] = v[3];
    __syncthreads();
    int rp = t >> 3, cp = (t & 7) * 4;
    int hd = c0 + rp;                 // (h*64+d)
    int b = r0 >> 10, j = (r0 & 1023) + cp;
    bf16x4 w = {tile[cp + 0][rp], tile[cp + 1][rp], tile[cp + 2][rp], tile[cp + 3][rp]};
    *(bf16x4*)&out[(size_t)(b * 1024 + hd) * 1024 + j] = w;
}

// ---------------------------------------------------------------------------
// MERGED GEMM, m97-style staging: global_load_lds width-16 into LINEAR
// [128][32] LDS tiles (no register round-trip, no padding — DMA dest is
// uniform-base + lane*16B: lane l covers row l>>2, k-slot (l&3)*8; wave wv
// round ri covers rows (ri*4+wv)*16..+15). 2 barriers/K-step as before.
// Blocks (after XCD swizzle, 768 = 8*96): o<256 -> Qb = xb@WqT (bx=o&7);
// o>=256 -> [K|V] = cb@WkvT (bx=(o-256)&15). XCD chunk=96 keeps the 6 MB
// of weights L2-resident per XCD.
// ---------------------------------------------------------------------------
__global__ __launch_bounds__(256) void gemm_all(const bf16* __restrict__ xb,
                                                const bf16* __restrict__ cb,
                                                const bf16* __restrict__ WqT,
                                                const bf16* __restrict__ WkvT,
                                                bf16* __restrict__ Qb,
                                                bf16* __restrict__ Kb,
                                                bf16* __restrict__ Vr) {
    __shared__ bf16 As[128 * 32];
    __shared__ bf16 Bs[128 * 32];
    const int t = threadIdx.x;
    const int wv = t >> 6, lane = t & 63, quad = lane >> 4, l15 = lane & 15;
    const int wr = wv >> 1, wc = wv & 1;
    // XCD-aware bijective swizzle (768 = 8 * 96).
    unsigned nb = blockIdx.x;
    unsigned o = (nb & 7) * 96 + (nb >> 3);
    const bf16 *A, *B; bool kv; int bx, by;
    if (o < 256) { A = xb; B = WqT; kv = false; bx = o & 7; by = o >> 3; }
    else { unsigned ob = o - 256; A = cb; B = WkvT; kv = true; bx = ob & 15; by = ob >> 4; }
    const int m0 = by * 128, n0 = bx * 128;
    const int srow = lane >> 2, scol = (lane & 3) * 8;   // staging lane geometry

    floatx4 acc[4][4] = {};

    for (int k0 = 0; k0 < 1024; k0 += 32) {
        __syncthreads();          // previous iter's LDS reads complete
#pragma unroll
        for (int ri = 0; ri < 2; ++ri) {
            const int rb = (ri * 4 + wv) * 16;            // uniform per wave
            gload16(&A[(size_t)(m0 + rb + srow) * 1024 + k0 + scol], &As[rb * 32]);
            gload16(&B[(size_t)(n0 + rb + srow) * 1024 + k0 + scol], &Bs[rb * 32]);
        }
        __syncthreads();          // drains vmcnt(0): tiles ready
        bf16x8 af[4], bfr[4];
#pragma unroll
        for (int mt = 0; mt < 4; ++mt)
            af[mt] = *(bf16x8*)&As[(wr * 64 + mt * 16 + l15) * 32 + quad * 8];
#pragma unroll
        for (int nt = 0; nt < 4; ++nt)
            bfr[nt] = *(bf16x8*)&Bs[(wc * 64 + nt * 16 + l15) * 32 + quad * 8];
#pragma unroll
        for (int mt = 0; mt < 4; ++mt)
#pragma unroll
            for (int nt = 0; nt < 4; ++nt)
                acc[mt][nt] = MFMA_BF16(af[mt], bfr[nt], acc[mt][nt]);
    }
#pragma unroll
    for (int mt = 0; mt < 4; ++mt)
#pragma unroll
        for (int nt = 0; nt < 4; ++nt)
#pragma unroll
            for (int r = 0; r < 4; ++r) {
                int m = m0 + wr * 64 + mt * 16 + quad * 4 + r;
                int n = n0 + wc * 64 + nt * 16 + l15;
                bf16 val = (bf16)acc[mt][nt][r];
                if (!kv) {
                    Qb[(size_t)m * 1024 + n] = val;
                } else {
                    if (n < 1024) Kb[(size_t)m * 1024 + n] = val;
                    else          Vr[(size_t)m * 1024 + (n - 1024)] = val;
                }
            }
}

// ---------------------------------------------------------------------------
// Softmax denominators (R9-identical): L[b][h][i] = sum_j exp(q.k*scale).
// grid (32,4,16) = 2048 blocks, XCD swizzle, hh-outer.
// ---------------------------------------------------------------------------
__global__ __launch_bounds__(256, 4) void denom_kernel(const bf16* __restrict__ Qb,
                                                       const bf16* __restrict__ Kb,
                                                       float* __restrict__ L) {
    const int t = threadIdx.x;
    const int wv = t >> 6, lane = t & 63, quad = lane >> 4, l15 = lane & 15;
    unsigned n = blockIdx.x + (blockIdx.y << 5) + (blockIdx.z << 7);   // 2048 total
    unsigned o = (n & 7) * 256 + (n >> 3);
    const int i0 = (o & 31) * 32;
    const int b  = (o >> 5) & 3;
    const int jz = o >> 7;
    const float scale = 0.125f;
    const bf16* Kbase = Kb + (size_t)b * 1024 * 1024;

    for (int hh = 0; hh < 4; ++hh) {
        const int h = wv * 4 + hh;
        bf16x8 qa[2][2];
#pragma unroll
        for (int it = 0; it < 2; ++it) {
            const bf16* qp = Qb + (size_t)(b * 1024 + i0 + it * 16 + l15) * 1024 +
                             h * 64 + quad * 8;
            qa[it][0] = *(const bf16x8*)qp;
            qa[it][1] = *(const bf16x8*)(qp + 32);
        }
        floatx4 se[2] = {};
#pragma unroll
        for (int jt = 0; jt < 4; ++jt) {
            int j = jz * 64 + jt * 16 + l15;
            const bf16* kp = Kbase + (size_t)j * 1024 + h * 64 + quad * 8;
            bf16x8 k0 = *(const bf16x8*)kp;
            bf16x8 k1 = *(const bf16x8*)(kp + 32);
#pragma unroll
            for (int it = 0; it < 2; ++it) {
                floatx4 c = {0.f, 0.f, 0.f, 0.f};
                c = MFMA_BF16(qa[it][0], k0, c);
                c = MFMA_BF16(qa[it][1], k1, c);
#pragma unroll
                for (int r = 0; r < 4; ++r) se[it][r] += __expf(c[r] * scale);
            }
        }
#pragma unroll
        for (int it = 0; it < 2; ++it)
#pragma unroll
            for (int r = 0; r < 4; ++r) {
                float s = se[it][r];
                s += __shfl_xor(s, 1); s += __shfl_xor(s, 2);
                s += __shfl_xor(s, 4); s += __shfl_xor(s, 8);
                if (l15 == 0)
                    atomicAdd(&L[(size_t)(b * 16 + h) * 1024 + i0 + it * 16 +
                                 quad * 4 + r], s);
            }
    }
}

// ---------------------------------------------------------------------------
// Main fused attention — R9/R3-identical (measured 150.9 us):
// grid (64,4,2), 512 thr, 2 barriers/jt, LDS 40960 (rot-640 Buf2, zero-hole),
// XCD swizzle. VGPR 60 / SGPR 48, no spills.
// ---------------------------------------------------------------------------
__global__ __launch_bounds__(512, 4) void attn_kernel(const bf16* __restrict__ Qb,
                                                      const bf16* __restrict__ Kb,
                                                      const bf16* __restrict__ Vt,
                                                      const float* __restrict__ L,
                                                      const bf16* __restrict__ WtcT,
                                                      const float* __restrict__ gamma,
                                                      const float* __restrict__ beta,
                                                      float* __restrict__ out) {
    __shared__ bf16 Buf1[512 * 20];        // [point p=i*32+jl][16 h + 4 pad]
    __shared__ bf16 Buf2[16 * 640];        // [g][rot(g) + i*40 + jl]
    const int t = threadIdx.x;
    const int wv = t >> 6, lane = t & 63, quad = lane >> 4, l15 = lane & 15;
    unsigned n = blockIdx.x + (blockIdx.y << 6) + (blockIdx.z << 8);   // 512 total
    unsigned o_idx = (n & 7) * 64 + (n >> 3);
    const int i0 = (o_idx & 63) * 16;
    const int b  = (o_idx >> 6) & 3;
    const int jz = o_idx >> 8;
    const float scale = 0.125f;

    if (t < 8) Buf2[2560 + t] = (bf16)0.f;   // zero region in the rot-hole
    const bf16* Zbuf = &Buf2[2560];

    bf16x8 a_wt = *(const bf16x8*)&WtcT[l15 * 32 + quad * 8];
    float gq[4], bq[4];
#pragma unroll
    for (int r = 0; r < 4; ++r) { gq[r] = gamma[quad * 4 + r]; bq[r] = beta[quad * 4 + r]; }

    bf16x8 qa[2][2];
    float invl[2][4];
#pragma unroll
    for (int hh = 0; hh < 2; ++hh) {
        int h = wv * 2 + hh;
        const bf16* qp = Qb + (size_t)(b * 1024 + i0 + l15) * 1024 + h * 64 + quad * 8;
        qa[hh][0] = *(const bf16x8*)qp;
        qa[hh][1] = *(const bf16x8*)(qp + 32);
#pragma unroll
        for (int r = 0; r < 4; ++r)
            invl[hh][r] = 1.f / L[(size_t)(b * 16 + h) * 1024 + i0 + quad * 4 + r];
    }

    const bf16* Kbase = Kb + (size_t)b * 1024 * 1024;
    const bf16* Vbase = Vt + (size_t)b * 16 * 64 * 1024;
    floatx4 o[2][4] = {};

    for (int jt = 0; jt < 16; ++jt) {
        const int j0 = jz * 512 + jt * 32;
#pragma unroll
        for (int ns = 0; ns < 2; ++ns) {
            floatx4 cw[2];
#pragma unroll
            for (int hh = 0; hh < 2; ++hh) {
                int h = wv * 2 + hh;
                const bf16* kp = Kbase + (size_t)(j0 + ns * 16 + l15) * 1024 + h * 64 + quad * 8;
                floatx4 c = {0.f, 0.f, 0.f, 0.f};
                c = MFMA_BF16(qa[hh][0], *(const bf16x8*)kp, c);
                c = MFMA_BF16(qa[hh][1], *(const bf16x8*)(kp + 32), c);
                cw[hh] = c;
            }
#pragma unroll
            for (int r = 0; r < 4; ++r) {
                bf16x2 pk = {(bf16)(__expf(cw[0][r] * scale) * invl[0][r]),
                             (bf16)(__expf(cw[1][r] * scale) * invl[1][r])};
                *(bf16x2*)&Buf1[((quad * 4 + r) * 32 + ns * 16 + l15) * 20 + wv * 2] = pk;
            }
        }
        __syncthreads();
#pragma unroll
        for (int grp = 0; grp < 4; ++grp) {
            int gi = wv * 4 + grp, ig = gi >> 1, jb = (gi & 1) * 16;
            int p = ig * 32 + jb + l15;
            const bf16* src = (quad < 2) ? &Buf1[p * 20 + quad * 8] : Zbuf;
            floatx4 c = {0.f, 0.f, 0.f, 0.f};
            c = MFMA_BF16(a_wt, *(const bf16x8*)src, c);
            float s2 = c[0] * c[0] + c[1] * c[1] + c[2] * c[2] + c[3] * c[3];
            s2 += __shfl_xor(s2, 16);
            s2 += __shfl_xor(s2, 32);
            float rs = rsqrtf(s2 * 0.0625f + 1e-5f);
#pragma unroll
            for (int r = 0; r < 4; ++r) {
                float w2 = c[r] * rs * gq[r] + bq[r];
                Buf2[(quad * 4 + r) * 640 + (quad & 1) * 8 + ig * 40 + jb + l15] = (bf16)w2;
            }
        }
        __syncthreads();
#pragma unroll
        for (int hh = 0; hh < 2; ++hh) {
            int g = wv * 2 + hh;
            bf16x8 a = *(bf16x8*)&Buf2[g * 640 + ((g >> 2) & 1) * 8 + l15 * 40 + quad * 8];
#pragma unroll
            for (int dt = 0; dt < 4; ++dt) {
                const bf16* vp = Vbase + (size_t)(g * 64 + dt * 16 + l15) * 1024 + j0 + quad * 8;
                o[hh][dt] = MFMA_BF16(a, *(const bf16x8*)vp, o[hh][dt]);
            }
        }
    }
#pragma unroll
    for (int hh = 0; hh < 2; ++hh) {
        int g = wv * 2 + hh;
#pragma unroll
        for (int dt = 0; dt < 4; ++dt)
#pragma unroll
            for (int r = 0; r < 4; ++r)
                atomicAdd(&out[(size_t)(b * 1024 + i0 + quad * 4 + r) * 1024 +
                               g * 64 + dt * 16 + l15], o[hh][dt][r]);
    }
}

extern "C" void kernel_launch(void* const* d_in, const int* in_sizes, int n_in,
                              void* d_out, int out_size, void* d_ws, size_t ws_size,
                              hipStream_t stream) {
    const float* x     = (const float*)d_in[0];
    const float* ctx   = (const float*)d_in[1];
    const float* Wq    = (const float*)d_in[2];
    const float* Wkv   = (const float*)d_in[3];
    const float* Wt    = (const float*)d_in[4];
    const float* gamma = (const float*)d_in[5];
    const float* beta  = (const float*)d_in[6];
    float* out = (float*)d_out;

    // ws layout (bf16 els): xb 4M | ctxb 4M | WqT 1M | WkvT 2M | Qb 4M | Kb 4M |
    //                       Vr 4M | Vt 4M | L (64K fp32) | WtcT (512 bf16)
    bf16* xb   = (bf16*)d_ws;
    bf16* cb   = xb + (size_t)4 * 1024 * 1024;
    bf16* WqT  = cb + (size_t)4 * 1024 * 1024;
    bf16* WkvT = WqT + (size_t)1024 * 1024;
    bf16* Qb   = WkvT + (size_t)2048 * 1024;
    bf16* Kb   = Qb + (size_t)4 * 1024 * 1024;
    bf16* Vr   = Kb + (size_t)4 * 1024 * 1024;
    bf16* Vt   = Vr + (size_t)4 * 1024 * 1024;
    float* L   = (float*)(Vt + (size_t)4 * 1024 * 1024);
    bf16* WtcT = (bf16*)(L + (size_t)4 * 16 * 1024);

    hipMemsetAsync(L, 0, (size_t)4 * 16 * 1024 * sizeof(float), stream);
    hipMemsetAsync(out, 0, (size_t)out_size * sizeof(float), stream);

    prep_kernel<<<7168, 256, 0, stream>>>(x, ctx, Wq, Wkv, xb, cb, WqT, WkvT);

    gemm_all<<<768, 256, 0, stream>>>(xb, cb, WqT, WkvT, Qb, Kb, Vr);
    vtrans_prep_kernel<<<4097, 256, 0, stream>>>(Vr, Vt, Wt, WtcT);

    denom_kernel<<<dim3(32, 4, 16), 256, 0, stream>>>(Qb, Kb, L);
    attn_kernel<<<dim3(64, 4, 2), 512, 0, stream>>>(Qb, Kb, Vt, L, WtcT, gamma, beta, out);
}